// Round 1
// baseline (105.933 us; speedup 1.0000x reference)
//
#include <hip/hip_runtime.h>

// DropStripes (SpecAugment along time axis, dim=2).
// x: [B=64, C=1, T=4096, F=256] fp32; bgn, distance: [B, 2] int32.
// out = x * keep[b,t], keep = NOT any stripe s covers t: t in [bgn, bgn+dist).
//
// Memory-bound masked copy. float4 per lane; one wave (64 lanes) = one full
// t-row (256 floats = 64 float4), so the drop decision is wave-uniform.

constexpr int T_DIM = 4096;          // time axis length
constexpr int F4 = 64;               // float4 per row (256 floats / 4)
constexpr int ROW_SHIFT = 6;         // log2(F4)
constexpr int B_SHIFT = 18;          // log2(T_DIM * F4) = log2(262144)

__global__ __launch_bounds__(256) void drop_stripes_kernel(
    const float4* __restrict__ x,
    const int*    __restrict__ bgn,
    const int*    __restrict__ dist,
    float4*       __restrict__ out,
    int n4) {
  const int stride = gridDim.x * blockDim.x;
  for (int i = blockIdx.x * blockDim.x + threadIdx.x; i < n4; i += stride) {
    const int t = (i >> ROW_SHIFT) & (T_DIM - 1);
    const int b = i >> B_SHIFT;
    // 2 stripes per sample; tiny table, stays in cache.
    const int b0 = bgn[b * 2 + 0], b1 = bgn[b * 2 + 1];
    const int d0 = dist[b * 2 + 0], d1 = dist[b * 2 + 1];
    const bool drop = (t >= b0 && t < b0 + d0) || (t >= b1 && t < b1 + d1);
    float4 v = make_float4(0.f, 0.f, 0.f, 0.f);
    if (!drop) {                      // wave-uniform: skip load on dropped rows
      v = x[i];
    }
    out[i] = v;
  }
}

extern "C" void kernel_launch(void* const* d_in, const int* in_sizes, int n_in,
                              void* d_out, int out_size, void* d_ws, size_t ws_size,
                              hipStream_t stream) {
  const float4* x   = (const float4*)d_in[0];
  const int* bgn    = (const int*)d_in[1];
  const int* dist   = (const int*)d_in[2];
  float4* out       = (float4*)d_out;

  const int n4 = out_size / 4;        // 16,777,216 float4s
  const int block = 256;
  const int grid = 2048;              // grid-stride, ~32 iters/thread
  drop_stripes_kernel<<<grid, block, 0, stream>>>(x, bgn, dist, out, n4);
}